// Round 9
// baseline (178.419 us; speedup 1.0000x reference)
//
#include <hip/hip_runtime.h>

typedef unsigned short u16;
typedef unsigned int u32;
typedef __attribute__((ext_vector_type(8))) short bf16x8;
typedef __attribute__((ext_vector_type(4))) float f32x4;

__device__ __forceinline__ u16 f2bf(float f) {
    u32 u = __builtin_bit_cast(u32, f);
    u += 0x7FFFu + ((u >> 16) & 1u);
    return (u16)(u >> 16);
}
__device__ __forceinline__ float bf2f(u16 s) {
    u32 u = ((u32)s) << 16;
    return __builtin_bit_cast(float, u);
}
__device__ __forceinline__ float sigm(float x) {
    return 1.0f / (1.0f + __expf(-x));
}
__device__ __forceinline__ void gload16(const u16* g, u16* l) {
    __builtin_amdgcn_global_load_lds(
        (const __attribute__((address_space(1))) void*)g,
        (__attribute__((address_space(3))) void*)l, 16, 0, 0);
}

// ---------------- P1: x (B,C,H,W) fp32 -> x' [p][c] bf16, p=(b*64+h)*64+w ----
__global__ __launch_bounds__(256) void transpose_in(const float* __restrict__ x,
                                                    u16* __restrict__ xp) {
    __shared__ float tile[64][65];
    int bid = blockIdx.x;
    int ct = bid & 3, h = (bid >> 2) & 63, b = bid >> 8;
    int t = threadIdx.x;
    int tr = t >> 4, tc = t & 15;
    const float* src = x + (((size_t)(b * 256 + ct * 64) * 64 + h) * 64);
#pragma unroll
    for (int i = 0; i < 4; ++i) {
        int c = tr + i * 16;
        float4 v = *(const float4*)(src + (size_t)c * 4096 + tc * 4);
        tile[c][tc * 4 + 0] = v.x;
        tile[c][tc * 4 + 1] = v.y;
        tile[c][tc * 4 + 2] = v.z;
        tile[c][tc * 4 + 3] = v.w;
    }
    __syncthreads();
    u16* dst = xp + ((size_t)((b * 64 + h) * 64)) * 256 + ct * 64;
#pragma unroll
    for (int i = 0; i < 4; ++i) {
        int w = tr + i * 16;
        ushort4 o;
        o.x = f2bf(tile[tc * 4 + 0][w]);
        o.y = f2bf(tile[tc * 4 + 1][w]);
        o.z = f2bf(tile[tc * 4 + 2][w]);
        o.w = f2bf(tile[tc * 4 + 3][w]);
        *(ushort4*)(dst + (size_t)w * 256 + tc * 4) = o;
    }
}

// ---------------- weight prep ------------------------------------------------
__global__ __launch_bounds__(256) void prep_w(const float* __restrict__ qw,
                                              const float* __restrict__ qb,
                                              const float* __restrict__ fw,
                                              const float* __restrict__ fb,
                                              float* __restrict__ wq0,
                                              u16* __restrict__ wkv,
                                              float* __restrict__ bkv,
                                              u16* __restrict__ wf,
                                              float* __restrict__ bff) {
    int i = blockIdx.x * 256 + threadIdx.x;
    if (i < 513 * 256) {
        int o = i >> 8, c = i & 255;
        float v = qw[i];
        if (o == 0) wq0[c] = v;
        else        wkv[(size_t)(o - 1) * 256 + c] = f2bf(v);
    }
    if (i < 65536) wf[i] = f2bf(fw[i]);
    if (i < 512)   bkv[i] = qb[i + 1];
    if (i < 256)   bff[i] = fb[i];
}

// ---------------- line_ctx: per-line q-dot + softmax + y = sc^T X + ----------
// ----------------           ctx = Wk*y + bk  (ctx out, 1 block per line) -----
template <int AXIS>
__global__ __launch_bounds__(256) void line_ctx(
    const u16* __restrict__ A, const u16* __restrict__ Wk,
    const float* __restrict__ wq0, const float* __restrict__ bkv,
    float* __restrict__ ctx) {
    __shared__ alignas(16) u16 Xl[64 * 256];
    __shared__ float ql[64];
    __shared__ float sc[64];
    __shared__ alignas(16) float ys[256];
    int t = threadIdx.x, lane = t & 63, wv = t >> 6;
    int l = blockIdx.x;
    auto prow = [&](int r) -> size_t {
        if (AXIS == 0) return (size_t)l * 64 + r;
        else           return (size_t)(l >> 6) * 4096 + (size_t)r * 64 + (l & 63);
    };
    // ---- stage line (swizzle: stored chunk = src chunk ^ (row&7)) ----
#pragma unroll
    for (int i = 0; i < 8; ++i) {
        int row = i * 8 + wv * 2 + (lane >> 5);
        int slot = (lane & 31) ^ (row & 7);
        gload16(A + prow(row) * 256 + slot * 8, &Xl[(i * 8 + wv * 2) * 256]);
    }
    __syncthreads();
    // ---- q-dot: 4 threads per row ----
    {
        int row = t >> 2, g = t & 3;
        const float* wp = wq0 + g * 64;
        float a = 0.f;
#pragma unroll
        for (int cc = 0; cc < 8; ++cc) {
            int slot = (g * 8 + cc) ^ (row & 7);
            bf16x8 v = *(const bf16x8*)&Xl[row * 256 + slot * 8];
#pragma unroll
            for (int j = 0; j < 8; ++j) a += bf2f((u16)v[j]) * wp[cc * 8 + j];
        }
        a += __shfl_xor(a, 1);
        a += __shfl_xor(a, 2);
        if (g == 0) ql[row] = a;
    }
    __syncthreads();
    // ---- softmax over 64 (wave 0) ----
    if (t < 64) {
        float qv = ql[t];
        float m = qv;
#pragma unroll
        for (int off = 32; off > 0; off >>= 1) m = fmaxf(m, __shfl_xor(m, off));
        float e = __expf(qv - m);
        float s = e;
#pragma unroll
        for (int off = 32; off > 0; off >>= 1) s += __shfl_xor(s, off);
        sc[t] = e / s;
    }
    __syncthreads();
    // ---- y[c] = sum_p sc[p] * X[p][c]; thread owns channel c = t ----
    {
        int chunk = t >> 3, e7 = t & 7;
        float a = 0.f;
#pragma unroll 8
        for (int p = 0; p < 64; ++p) {
            int slot = chunk ^ (p & 7);
            a += bf2f(Xl[p * 256 + slot * 8 + e7]) * sc[p];
        }
        ys[t] = a;
    }
    __syncthreads();
    // ---- ctx[c] = Wk[c,:].y + bk[c] ----
    {
        const u16* wk = Wk + (size_t)t * 256;
        float a = 0.f;
#pragma unroll
        for (int kc = 0; kc < 32; ++kc) {
            bf16x8 w = *(const bf16x8*)(wk + kc * 8);
#pragma unroll
            for (int j = 0; j < 8; ++j) a += bf2f((u16)w[j]) * ys[kc * 8 + j];
        }
        ctx[(size_t)l * 256 + t] = a + bkv[t];
    }
}

// ---------------- val_gate v2: swapped MFMA (lane = 4 consecutive channels) --
// G = X + sigmoid(X.Wv^T + bv) * ctx[line]; ctx staged to LDS (2 lines/block).
template <int AXIS>
__global__ __launch_bounds__(256, 2) void val_gate(
    const u16* __restrict__ A, const u16* __restrict__ Wv,
    const float* __restrict__ bv, const float* __restrict__ ctx,
    u16* __restrict__ G) {
    int h = blockIdx.x;
    int xcd = h & 7, slot = h >> 3;
    int otile = slot & 1, ptile = xcd * 64 + (slot >> 1);
    __shared__ alignas(16) u16 Asm[128 * 64];
    __shared__ alignas(16) u16 Bsm[128 * 64];
    __shared__ alignas(16) float ctxs[2][128];
    int o0 = otile * 128;
    int t = threadIdx.x, lane = t & 63, wv = t >> 6;
    int arow = lane & 15, kgrp = lane >> 4, l7 = lane & 7;
    int rowhalf = wv & 1, chhalf = wv >> 1;
    auto prow = [&](int r) -> size_t {
        if (AXIS == 0) return (size_t)ptile * 128 + r;
        else           return (size_t)(ptile >> 5) * 4096 + (size_t)(r & 63) * 64 +
                              ((ptile & 31) * 2) + (r >> 6);
    };
    int lbase = (AXIS == 0) ? (ptile * 2) : ((ptile >> 5) * 64 + (ptile & 31) * 2);
    {
        int ll = t >> 7, cl = t & 127;
        ctxs[ll][cl] = ctx[(size_t)(lbase + ll) * 256 + o0 + cl];
    }
    f32x4 zero = {0.f, 0.f, 0.f, 0.f};
    f32x4 acc[4][4];
#pragma unroll
    for (int i = 0; i < 4; ++i)
#pragma unroll
        for (int jj = 0; jj < 4; ++jj) acc[i][jj] = zero;

    for (int k0 = 0; k0 < 256; k0 += 64) {
        __syncthreads();
#pragma unroll
        for (int it = 0; it < 4; ++it) {
            int r0 = it * 32 + wv * 8;
            int rr = r0 + (lane >> 3);
            int chs = ((l7 ^ (lane >> 3)) * 8);
            gload16(A + prow(rr) * 256 + k0 + chs, &Asm[r0 * 64]);
            gload16(Wv + (size_t)(o0 + rr) * 256 + k0 + chs, &Bsm[r0 * 64]);
        }
        __syncthreads();
#pragma unroll
        for (int kk = 0; kk < 64; kk += 32) {
            int soff = (((kk >> 3) + kgrp) ^ l7) << 3;
            bf16x8 xf[4], wf[4];
#pragma unroll
            for (int xi = 0; xi < 4; ++xi)
                xf[xi] = *(const bf16x8*)&Asm[(rowhalf * 64 + xi * 16 + arow) * 64 + soff];
#pragma unroll
            for (int wi = 0; wi < 4; ++wi)
                wf[wi] = *(const bf16x8*)&Bsm[(chhalf * 64 + wi * 16 + arow) * 64 + soff];
#pragma unroll
            for (int wi = 0; wi < 4; ++wi)
#pragma unroll
                for (int xi = 0; xi < 4; ++xi)
                    acc[wi][xi] = __builtin_amdgcn_mfma_f32_16x16x32_bf16(
                        wf[wi], xf[xi], acc[wi][xi], 0, 0, 0);
        }
    }
    // epilogue: lane holds 4 consecutive channels -> ushort4 I/O
#pragma unroll
    for (int wi = 0; wi < 4; ++wi) {
        int chl = chhalf * 64 + wi * 16 + kgrp * 4;
        int ch = o0 + chl;
        f32x4 bq = *(const f32x4*)&bv[ch];
        f32x4 cx = *(const f32x4*)&ctxs[rowhalf][chl];
#pragma unroll
        for (int xi = 0; xi < 4; ++xi) {
            int row = rowhalf * 64 + xi * 16 + arow;
            size_t p = prow(row);
            ushort4 xv = *(const ushort4*)(A + p * 256 + ch);
            ushort4 o;
            o.x = f2bf(bf2f(xv.x) + sigm(acc[wi][xi][0] + bq[0]) * cx[0]);
            o.y = f2bf(bf2f(xv.y) + sigm(acc[wi][xi][1] + bq[1]) * cx[1]);
            o.z = f2bf(bf2f(xv.z) + sigm(acc[wi][xi][2] + bq[2]) * cx[2]);
            o.w = f2bf(bf2f(xv.w) + sigm(acc[wi][xi][3] + bq[3]) * cx[3]);
            *(ushort4*)(G + p * 256 + ch) = o;
        }
    }
}

// ---------------- fusion GEMM: MODE 1 = bf16 out (swapped acc, ushort4 store),
// ----------------              MODE 2 = fp32 out via LDS transpose (coalesced)
template <int MODE>
__global__ __launch_bounds__(256, 2) void gemm_k(
    const u16* __restrict__ A, const u16* __restrict__ Bw,
    const float* __restrict__ bias,
    u16* __restrict__ bOut, float* __restrict__ fOut) {
    int h = blockIdx.x;
    int xcd = h & 7, slot = h >> 3;
    int otile = slot & 1, ptile = xcd * 64 + (slot >> 1);
    __shared__ alignas(16) u16 Asm[128 * 64];
    __shared__ alignas(16) u16 Bsm[128 * 64];
    __shared__ alignas(16) float tb[(MODE == 2) ? 64 * 132 : 4];
    int p0 = ptile * 128, o0 = otile * 128;
    int t = threadIdx.x, lane = t & 63, wv = t >> 6;
    int wm = (wv >> 1) * 64, wn = (wv & 1) * 64;
    int l7 = lane & 7;
    int srcoff = (lane >> 3) * 256 + (((lane & 7) ^ (lane >> 3)) * 8);
    int arow = lane & 15, kgrp = lane >> 4;
    f32x4 zero = {0.f, 0.f, 0.f, 0.f};
    f32x4 acc[4][4];
#pragma unroll
    for (int i = 0; i < 4; ++i)
#pragma unroll
        for (int jj = 0; jj < 4; ++jj) acc[i][jj] = zero;

    for (int k0 = 0; k0 < 256; k0 += 64) {
        __syncthreads();
#pragma unroll
        for (int it = 0; it < 4; ++it) {
            int r0 = it * 32 + wv * 8;
            gload16(A + (size_t)(p0 + r0) * 256 + k0 + srcoff, &Asm[r0 * 64]);
            gload16(Bw + (size_t)(o0 + r0) * 256 + k0 + srcoff, &Bsm[r0 * 64]);
        }
        __syncthreads();
#pragma unroll
        for (int kk = 0; kk < 64; kk += 32) {
            int soff = (((kk >> 3) + kgrp) ^ l7) << 3;
            bf16x8 af[4], bfv[4];
#pragma unroll
            for (int mi = 0; mi < 4; ++mi)
                af[mi] = *(const bf16x8*)&Asm[(wm + mi * 16 + arow) * 64 + soff];
#pragma unroll
            for (int ni = 0; ni < 4; ++ni)
                bfv[ni] = *(const bf16x8*)&Bsm[(wn + ni * 16 + arow) * 64 + soff];
            if (MODE == 1) {
                // swapped: acc[ni][mi] rows=cols(B), lane&15 = A-row
#pragma unroll
                for (int ni = 0; ni < 4; ++ni)
#pragma unroll
                    for (int mi = 0; mi < 4; ++mi)
                        acc[ni][mi] = __builtin_amdgcn_mfma_f32_16x16x32_bf16(
                            bfv[ni], af[mi], acc[ni][mi], 0, 0, 0);
            } else {
#pragma unroll
                for (int mi = 0; mi < 4; ++mi)
#pragma unroll
                    for (int ni = 0; ni < 4; ++ni)
                        acc[mi][ni] = __builtin_amdgcn_mfma_f32_16x16x32_bf16(
                            af[mi], bfv[ni], acc[mi][ni], 0, 0, 0);
            }
        }
    }
    if (MODE == 1) {
        // lane holds 4 consecutive cols -> ushort4 stores
#pragma unroll
        for (int ni = 0; ni < 4; ++ni) {
            int col0 = o0 + wn + ni * 16 + kgrp * 4;
            f32x4 bq = *(const f32x4*)&bias[col0];
#pragma unroll
            for (int mi = 0; mi < 4; ++mi) {
                int row = p0 + wm + mi * 16 + arow;
                ushort4 o;
                o.x = f2bf(acc[ni][mi][0] + bq[0]);
                o.y = f2bf(acc[ni][mi][1] + bq[1]);
                o.z = f2bf(acc[ni][mi][2] + bq[2]);
                o.w = f2bf(acc[ni][mi][3] + bq[3]);
                *(ushort4*)(bOut + (size_t)row * 256 + col0) = o;
            }
        }
    } else {
        // transpose via LDS, then coalesced float4 stores along HW
        int bb = p0 >> 12, pl = p0 & 4095;
#pragma unroll
        for (int cp = 0; cp < 2; ++cp) {
            if ((wv & 1) == cp) {
#pragma unroll
                for (int ni = 0; ni < 4; ++ni) {
                    int c = ni * 16 + arow;
                    float bvv = bias[o0 + cp * 64 + c];
#pragma unroll
                    for (int mi = 0; mi < 4; ++mi) {
                        int r0w = wm + mi * 16 + kgrp * 4;
                        f32x4 v;
                        v[0] = acc[mi][ni][0] + bvv;
                        v[1] = acc[mi][ni][1] + bvv;
                        v[2] = acc[mi][ni][2] + bvv;
                        v[3] = acc[mi][ni][3] + bvv;
                        *(f32x4*)&tb[c * 132 + r0w] = v;
                    }
                }
            }
            __syncthreads();
#pragma unroll
            for (int i = 0; i < 8; ++i) {
                int c = i * 8 + (t >> 5);
                f32x4 v = *(const f32x4*)&tb[c * 132 + (t & 31) * 4];
                *(float4*)&fOut[(size_t)(bb * 256 + o0 + cp * 64 + c) * 4096 +
                                pl + (t & 31) * 4] = *(float4*)&v;
            }
            if (cp == 0) __syncthreads();
        }
    }
}

// ---------------- host ----------------
extern "C" void kernel_launch(void* const* d_in, const int* in_sizes, int n_in,
                              void* d_out, int out_size, void* d_ws, size_t ws_size,
                              hipStream_t stream) {
    const float* x   = (const float*)d_in[0];
    const float* qWw = (const float*)d_in[1];
    const float* qWb = (const float*)d_in[2];
    const float* qHw = (const float*)d_in[3];
    const float* qHb = (const float*)d_in[4];
    const float* fWw = (const float*)d_in[5];
    const float* fWb = (const float*)d_in[6];
    const float* fHw = (const float*)d_in[7];
    const float* fHb = (const float*)d_in[8];
    float* out = (float*)d_out;

    char* ws = (char*)d_ws;
    size_t off = 0;
    auto carve = [&](size_t bytes) -> void* {
        off = (off + 255) & ~(size_t)255;
        void* p = ws + off;
        off += bytes;
        return p;
    };
    const size_t P = 65536;
    u16*   xp  = (u16*)carve(P * 256 * 2);   // x'
    u16*   kb  = (u16*)carve(P * 256 * 2);   // G (both stages)
    u16*   vb  = (u16*)carve(P * 256 * 2);   // x_w'
    float* ctxb = (float*)carve(1024 * 256 * 4);
    float* wq01 = (float*)carve(256 * 4);
    u16*   wkv1 = (u16*)carve(512 * 256 * 2);
    float* bkv1 = (float*)carve(512 * 4);
    u16*   wf1  = (u16*)carve(65536 * 2);
    float* bf1  = (float*)carve(256 * 4);
    float* wq02 = (float*)carve(256 * 4);
    u16*   wkv2 = (u16*)carve(512 * 256 * 2);
    float* bkv2 = (float*)carve(512 * 4);
    u16*   wf2  = (u16*)carve(65536 * 2);
    float* bf2  = (float*)carve(256 * 4);

    prep_w<<<513, 256, 0, stream>>>(qWw, qWb, fWw, fWb, wq01, wkv1, bkv1, wf1, bf1);
    prep_w<<<513, 256, 0, stream>>>(qHw, qHb, fHw, fHb, wq02, wkv2, bkv2, wf2, bf2);
    transpose_in<<<4096, 256, 0, stream>>>(x, xp);

    // ---- stage 1 (axis = W) ----
    line_ctx<0><<<1024, 256, 0, stream>>>(xp, wkv1, wq01, bkv1, ctxb);
    val_gate<0><<<1024, 256, 0, stream>>>(xp, wkv1 + 256 * 256, bkv1 + 256,
                                          ctxb, kb);
    gemm_k<1><<<1024, 256, 0, stream>>>(kb, wf1, bf1, vb, nullptr);   // x_w' -> vb
    // ---- stage 2 (axis = H) ----
    line_ctx<1><<<1024, 256, 0, stream>>>(vb, wkv2, wq02, bkv2, ctxb);
    val_gate<1><<<1024, 256, 0, stream>>>(vb, wkv2 + 256 * 256, bkv2 + 256,
                                          ctxb, kb);
    gemm_k<2><<<1024, 256, 0, stream>>>(kb, wf2, bf2, nullptr, out);
    (void)in_sizes; (void)n_in; (void)out_size; (void)ws_size;
}

// Round 10
// 174.564 us; speedup vs baseline: 1.0221x; 1.0221x over previous
//
#include <hip/hip_runtime.h>

typedef unsigned short u16;
typedef unsigned int u32;
typedef __attribute__((ext_vector_type(8))) short bf16x8;
typedef __attribute__((ext_vector_type(4))) float f32x4;

__device__ __forceinline__ u16 f2bf(float f) {
    u32 u = __builtin_bit_cast(u32, f);
    u += 0x7FFFu + ((u >> 16) & 1u);
    return (u16)(u >> 16);
}
__device__ __forceinline__ float bf2f(u16 s) {
    u32 u = ((u32)s) << 16;
    return __builtin_bit_cast(float, u);
}
__device__ __forceinline__ float sigm(float x) {
    return 1.0f / (1.0f + __expf(-x));
}
__device__ __forceinline__ void gload16(const u16* g, u16* l) {
    __builtin_amdgcn_global_load_lds(
        (const __attribute__((address_space(1))) void*)g,
        (__attribute__((address_space(3))) void*)l, 16, 0, 0);
}

// ---------------- P1: x (B,C,H,W) fp32 -> x' [p][c] bf16, p=(b*64+h)*64+w ----
__global__ __launch_bounds__(256) void transpose_in(const float* __restrict__ x,
                                                    u16* __restrict__ xp) {
    __shared__ float tile[64][65];
    int bid = blockIdx.x;
    int ct = bid & 3, h = (bid >> 2) & 63, b = bid >> 8;
    int t = threadIdx.x;
    int tr = t >> 4, tc = t & 15;
    const float* src = x + (((size_t)(b * 256 + ct * 64) * 64 + h) * 64);
#pragma unroll
    for (int i = 0; i < 4; ++i) {
        int c = tr + i * 16;
        float4 v = *(const float4*)(src + (size_t)c * 4096 + tc * 4);
        tile[c][tc * 4 + 0] = v.x;
        tile[c][tc * 4 + 1] = v.y;
        tile[c][tc * 4 + 2] = v.z;
        tile[c][tc * 4 + 3] = v.w;
    }
    __syncthreads();
    u16* dst = xp + ((size_t)((b * 64 + h) * 64)) * 256 + ct * 64;
#pragma unroll
    for (int i = 0; i < 4; ++i) {
        int w = tr + i * 16;
        ushort4 o;
        o.x = f2bf(tile[tc * 4 + 0][w]);
        o.y = f2bf(tile[tc * 4 + 1][w]);
        o.z = f2bf(tile[tc * 4 + 2][w]);
        o.w = f2bf(tile[tc * 4 + 3][w]);
        *(ushort4*)(dst + (size_t)w * 256 + tc * 4) = o;
    }
}

// ---------------- weight prep ------------------------------------------------
__global__ __launch_bounds__(256) void prep_w(const float* __restrict__ qw,
                                              const float* __restrict__ qb,
                                              const float* __restrict__ fw,
                                              const float* __restrict__ fb,
                                              float* __restrict__ wq0,
                                              u16* __restrict__ wkv,
                                              float* __restrict__ bkv,
                                              u16* __restrict__ wf,
                                              float* __restrict__ bff) {
    int i = blockIdx.x * 256 + threadIdx.x;
    if (i < 513 * 256) {
        int o = i >> 8, c = i & 255;
        float v = qw[i];
        if (o == 0) wq0[c] = v;
        else        wkv[(size_t)(o - 1) * 256 + c] = f2bf(v);
    }
    if (i < 65536) wf[i] = f2bf(fw[i]);
    if (i < 512)   bkv[i] = qb[i + 1];
    if (i < 256)   bff[i] = fb[i];
}

// ---------------- line_ctx: per-line q-dot + softmax + y = sc^T X + ----------
// ----------------           ctx = Wk*y + bk  (ctx out, 1 block per line) -----
template <int AXIS>
__global__ __launch_bounds__(256) void line_ctx(
    const u16* __restrict__ A, const u16* __restrict__ Wk,
    const float* __restrict__ wq0, const float* __restrict__ bkv,
    float* __restrict__ ctx) {
    __shared__ alignas(16) u16 Xl[64 * 256];
    __shared__ float ql[64];
    __shared__ float sc[64];
    __shared__ alignas(16) float ys[256];
    int t = threadIdx.x, lane = t & 63, wv = t >> 6;
    int l = blockIdx.x;
    auto prow = [&](int r) -> size_t {
        if (AXIS == 0) return (size_t)l * 64 + r;
        else           return (size_t)(l >> 6) * 4096 + (size_t)r * 64 + (l & 63);
    };
    // ---- stage line (swizzle: stored chunk = src chunk ^ (row&7)) ----
#pragma unroll
    for (int i = 0; i < 8; ++i) {
        int row = i * 8 + wv * 2 + (lane >> 5);
        int slot = (lane & 31) ^ (row & 7);
        gload16(A + prow(row) * 256 + slot * 8, &Xl[(i * 8 + wv * 2) * 256]);
    }
    __syncthreads();
    // ---- q-dot: 4 threads per row ----
    {
        int row = t >> 2, g = t & 3;
        const float* wp = wq0 + g * 64;
        float a = 0.f;
#pragma unroll
        for (int cc = 0; cc < 8; ++cc) {
            int slot = (g * 8 + cc) ^ (row & 7);
            bf16x8 v = *(const bf16x8*)&Xl[row * 256 + slot * 8];
#pragma unroll
            for (int j = 0; j < 8; ++j) a += bf2f((u16)v[j]) * wp[cc * 8 + j];
        }
        a += __shfl_xor(a, 1);
        a += __shfl_xor(a, 2);
        if (g == 0) ql[row] = a;
    }
    __syncthreads();
    // ---- softmax over 64 (wave 0) ----
    if (t < 64) {
        float qv = ql[t];
        float m = qv;
#pragma unroll
        for (int off = 32; off > 0; off >>= 1) m = fmaxf(m, __shfl_xor(m, off));
        float e = __expf(qv - m);
        float s = e;
#pragma unroll
        for (int off = 32; off > 0; off >>= 1) s += __shfl_xor(s, off);
        sc[t] = e / s;
    }
    __syncthreads();
    // ---- y[c] = sum_p sc[p] * X[p][c]; thread owns channel c = t ----
    {
        int chunk = t >> 3, e7 = t & 7;
        float a = 0.f;
#pragma unroll 8
        for (int p = 0; p < 64; ++p) {
            int slot = chunk ^ (p & 7);
            a += bf2f(Xl[p * 256 + slot * 8 + e7]) * sc[p];
        }
        ys[t] = a;
    }
    __syncthreads();
    // ---- ctx[c] = Wk[c,:].y + bk[c] ----
    {
        const u16* wk = Wk + (size_t)t * 256;
        float a = 0.f;
#pragma unroll
        for (int kc = 0; kc < 32; ++kc) {
            bf16x8 w = *(const bf16x8*)(wk + kc * 8);
#pragma unroll
            for (int j = 0; j < 8; ++j) a += bf2f((u16)w[j]) * ys[kc * 8 + j];
        }
        ctx[(size_t)l * 256 + t] = a + bkv[t];
    }
}

// ---------------- val_gate v3: full A panel in LDS (80KB total = 2 blk/CU) ---
// G = X + sigmoid(X.Wv^T + bv) * ctx[line]; x readback + ctx from LDS/regs.
// Swapped MFMA: lane holds 4 consecutive channels.
template <int AXIS>
__global__ __launch_bounds__(256, 2) void val_gate(
    const u16* __restrict__ A, const u16* __restrict__ Wv,
    const float* __restrict__ bv, const float* __restrict__ ctx,
    u16* __restrict__ G) {
    __shared__ alignas(16) u16 Asm[128 * 256];  // 64 KB full panel
    __shared__ alignas(16) u16 Bsm[128 * 64];   // 16 KB Wv k-tile
    int h = blockIdx.x;
    int xcd = h & 7, slot = h >> 3;
    int otile = slot & 1, ptile = xcd * 64 + (slot >> 1);
    int o0 = otile * 128;
    int t = threadIdx.x, lane = t & 63, wv = t >> 6;
    int arow = lane & 15, kgrp = lane >> 4, l7 = lane & 7;
    int wm = (wv >> 1) * 64, wn = (wv & 1) * 64;
    auto prow = [&](int r) -> size_t {
        if (AXIS == 0) return (size_t)ptile * 128 + r;
        else           return (size_t)(ptile >> 5) * 4096 + (size_t)(r & 63) * 64 +
                              ((ptile & 31) * 2) + (r >> 6);
    };
    int lbase = (AXIS == 0) ? (ptile * 2) : ((ptile >> 5) * 64 + (ptile & 31) * 2);
    // per-thread ctx + bias registers (thread's rows are all in line lbase+(wv>>1))
    f32x4 cxr[4], bvr[4];
    {
        int line = lbase + (wv >> 1);
#pragma unroll
        for (int wi = 0; wi < 4; ++wi) {
            int ch = o0 + wn + wi * 16 + kgrp * 4;
            cxr[wi] = *(const f32x4*)&ctx[(size_t)line * 256 + ch];
            bvr[wi] = *(const f32x4*)&bv[ch];
        }
    }
    // ---- stage full A panel (16 rounds x 8 rows) ----
#pragma unroll
    for (int i = 0; i < 16; ++i) {
        int row = i * 8 + wv * 2 + (lane >> 5);
        int slotc = (lane & 31) ^ (row & 7);
        gload16(A + prow(row) * 256 + slotc * 8, &Asm[(i * 8 + wv * 2) * 256]);
    }
    int srcoff = (lane >> 3) * 256 + (((lane & 7) ^ (lane >> 3)) * 8);
    f32x4 zero = {0.f, 0.f, 0.f, 0.f};
    f32x4 acc[4][4];
#pragma unroll
    for (int i = 0; i < 4; ++i)
#pragma unroll
        for (int jj = 0; jj < 4; ++jj) acc[i][jj] = zero;

    for (int k0 = 0; k0 < 256; k0 += 64) {
        __syncthreads();
#pragma unroll
        for (int it = 0; it < 4; ++it) {
            int r0 = it * 32 + wv * 8;
            gload16(Wv + (size_t)(o0 + r0) * 256 + k0 + srcoff, &Bsm[r0 * 64]);
        }
        __syncthreads();
#pragma unroll
        for (int kk = 0; kk < 64; kk += 32) {
            int soff = (((kk >> 3) + kgrp) ^ l7) << 3;
            bf16x8 xf[4], wf[4];
#pragma unroll
            for (int xi = 0; xi < 4; ++xi) {
                int p = wm + xi * 16 + arow;
                int chunk = ((k0 + kk) >> 3) + kgrp;
                int slt = chunk ^ (p & 7);
                xf[xi] = *(const bf16x8*)&Asm[p * 256 + slt * 8];
            }
#pragma unroll
            for (int wi = 0; wi < 4; ++wi)
                wf[wi] = *(const bf16x8*)&Bsm[(wn + wi * 16 + arow) * 64 + soff];
#pragma unroll
            for (int wi = 0; wi < 4; ++wi)
#pragma unroll
                for (int xi = 0; xi < 4; ++xi)
                    acc[wi][xi] = __builtin_amdgcn_mfma_f32_16x16x32_bf16(
                        wf[wi], xf[xi], acc[wi][xi], 0, 0, 0);
        }
    }
    // ---- epilogue: x from LDS, ushort4 G stores ----
#pragma unroll
    for (int wi = 0; wi < 4; ++wi) {
        int chl = wn + wi * 16 + kgrp * 4;  // 0..127 local (within o-half)
        int ch = o0 + chl;
        f32x4 bq = bvr[wi];
        f32x4 cx = cxr[wi];
#pragma unroll
        for (int xi = 0; xi < 4; ++xi) {
            int p = wm + xi * 16 + arow;
            int slt = (ch >> 3) ^ (p & 7);
            ushort4 xv = *(const ushort4*)&Asm[p * 256 + slt * 8 + (ch & 7)];
            ushort4 o;
            o.x = f2bf(bf2f(xv.x) + sigm(acc[wi][xi][0] + bq[0]) * cx[0]);
            o.y = f2bf(bf2f(xv.y) + sigm(acc[wi][xi][1] + bq[1]) * cx[1]);
            o.z = f2bf(bf2f(xv.z) + sigm(acc[wi][xi][2] + bq[2]) * cx[2]);
            o.w = f2bf(bf2f(xv.w) + sigm(acc[wi][xi][3] + bq[3]) * cx[3]);
            *(ushort4*)(G + prow(p) * 256 + ch) = o;
        }
    }
}

// ---------------- fusion GEMM: MODE 1 = bf16 out (swapped acc, ushort4 store),
// ----------------              MODE 2 = fp32 transposed out via direct float4
template <int MODE>
__global__ __launch_bounds__(256, 2) void gemm_k(
    const u16* __restrict__ A, const u16* __restrict__ Bw,
    const float* __restrict__ bias,
    u16* __restrict__ bOut, float* __restrict__ fOut) {
    int h = blockIdx.x;
    int xcd = h & 7, slot = h >> 3;
    int otile = slot & 1, ptile = xcd * 64 + (slot >> 1);
    __shared__ alignas(16) u16 Asm[128 * 64];
    __shared__ alignas(16) u16 Bsm[128 * 64];
    int p0 = ptile * 128, o0 = otile * 128;
    int t = threadIdx.x, lane = t & 63, wv = t >> 6;
    int wm = (wv >> 1) * 64, wn = (wv & 1) * 64;
    int l7 = lane & 7;
    int srcoff = (lane >> 3) * 256 + (((lane & 7) ^ (lane >> 3)) * 8);
    int arow = lane & 15, kgrp = lane >> 4;
    f32x4 zero = {0.f, 0.f, 0.f, 0.f};
    f32x4 acc[4][4];
#pragma unroll
    for (int i = 0; i < 4; ++i)
#pragma unroll
        for (int jj = 0; jj < 4; ++jj) acc[i][jj] = zero;

    for (int k0 = 0; k0 < 256; k0 += 64) {
        __syncthreads();
#pragma unroll
        for (int it = 0; it < 4; ++it) {
            int r0 = it * 32 + wv * 8;
            gload16(A + (size_t)(p0 + r0) * 256 + k0 + srcoff, &Asm[r0 * 64]);
            gload16(Bw + (size_t)(o0 + r0) * 256 + k0 + srcoff, &Bsm[r0 * 64]);
        }
        __syncthreads();
#pragma unroll
        for (int kk = 0; kk < 64; kk += 32) {
            int soff = (((kk >> 3) + kgrp) ^ l7) << 3;
            bf16x8 af[4], bfv[4];
#pragma unroll
            for (int mi = 0; mi < 4; ++mi)
                af[mi] = *(const bf16x8*)&Asm[(wm + mi * 16 + arow) * 64 + soff];
#pragma unroll
            for (int ni = 0; ni < 4; ++ni)
                bfv[ni] = *(const bf16x8*)&Bsm[(wn + ni * 16 + arow) * 64 + soff];
            if (MODE == 1) {
                // swapped: lane holds 4 consecutive output cols
#pragma unroll
                for (int ni = 0; ni < 4; ++ni)
#pragma unroll
                    for (int mi = 0; mi < 4; ++mi)
                        acc[ni][mi] = __builtin_amdgcn_mfma_f32_16x16x32_bf16(
                            bfv[ni], af[mi], acc[ni][mi], 0, 0, 0);
            } else {
                // normal: lane holds 4 consecutive rows (p) for fixed col
#pragma unroll
                for (int mi = 0; mi < 4; ++mi)
#pragma unroll
                    for (int ni = 0; ni < 4; ++ni)
                        acc[mi][ni] = __builtin_amdgcn_mfma_f32_16x16x32_bf16(
                            af[mi], bfv[ni], acc[mi][ni], 0, 0, 0);
            }
        }
    }
    if (MODE == 1) {
#pragma unroll
        for (int ni = 0; ni < 4; ++ni) {
            int col0 = o0 + wn + ni * 16 + kgrp * 4;
            f32x4 bq = *(const f32x4*)&bias[col0];
#pragma unroll
            for (int mi = 0; mi < 4; ++mi) {
                int row = p0 + wm + mi * 16 + arow;
                ushort4 o;
                o.x = f2bf(acc[ni][mi][0] + bq[0]);
                o.y = f2bf(acc[ni][mi][1] + bq[1]);
                o.z = f2bf(acc[ni][mi][2] + bq[2]);
                o.w = f2bf(acc[ni][mi][3] + bq[3]);
                *(ushort4*)(bOut + (size_t)row * 256 + col0) = o;
            }
        }
    } else {
        // direct float4 stores: 4 consecutive p per acc reg-quad
        int bb = p0 >> 12;
#pragma unroll
        for (int mi = 0; mi < 4; ++mi) {
            int row0 = p0 + wm + mi * 16 + kgrp * 4;
#pragma unroll
            for (int ni = 0; ni < 4; ++ni) {
                int col = o0 + wn + ni * 16 + arow;
                float bvv = bias[col];
                f32x4 v = acc[mi][ni];
                v[0] += bvv; v[1] += bvv; v[2] += bvv; v[3] += bvv;
                *(f32x4*)&fOut[((size_t)(bb * 256 + col)) * 4096 + (row0 & 4095)] = v;
            }
        }
    }
}

// ---------------- host ----------------
extern "C" void kernel_launch(void* const* d_in, const int* in_sizes, int n_in,
                              void* d_out, int out_size, void* d_ws, size_t ws_size,
                              hipStream_t stream) {
    const float* x   = (const float*)d_in[0];
    const float* qWw = (const float*)d_in[1];
    const float* qWb = (const float*)d_in[2];
    const float* qHw = (const float*)d_in[3];
    const float* qHb = (const float*)d_in[4];
    const float* fWw = (const float*)d_in[5];
    const float* fWb = (const float*)d_in[6];
    const float* fHw = (const float*)d_in[7];
    const float* fHb = (const float*)d_in[8];
    float* out = (float*)d_out;

    char* ws = (char*)d_ws;
    size_t off = 0;
    auto carve = [&](size_t bytes) -> void* {
        off = (off + 255) & ~(size_t)255;
        void* p = ws + off;
        off += bytes;
        return p;
    };
    const size_t P = 65536;
    u16*   xp  = (u16*)carve(P * 256 * 2);   // x'
    u16*   kb  = (u16*)carve(P * 256 * 2);   // G (both stages)
    u16*   vb  = (u16*)carve(P * 256 * 2);   // x_w'
    float* ctxb = (float*)carve(1024 * 256 * 4);
    float* wq01 = (float*)carve(256 * 4);
    u16*   wkv1 = (u16*)carve(512 * 256 * 2);
    float* bkv1 = (float*)carve(512 * 4);
    u16*   wf1  = (u16*)carve(65536 * 2);
    float* bf1  = (float*)carve(256 * 4);
    float* wq02 = (float*)carve(256 * 4);
    u16*   wkv2 = (u16*)carve(512 * 256 * 2);
    float* bkv2 = (float*)carve(512 * 4);
    u16*   wf2  = (u16*)carve(65536 * 2);
    float* bf2  = (float*)carve(256 * 4);

    prep_w<<<513, 256, 0, stream>>>(qWw, qWb, fWw, fWb, wq01, wkv1, bkv1, wf1, bf1);
    prep_w<<<513, 256, 0, stream>>>(qHw, qHb, fHw, fHb, wq02, wkv2, bkv2, wf2, bf2);
    transpose_in<<<4096, 256, 0, stream>>>(x, xp);

    // ---- stage 1 (axis = W) ----
    line_ctx<0><<<1024, 256, 0, stream>>>(xp, wkv1, wq01, bkv1, ctxb);
    val_gate<0><<<1024, 256, 0, stream>>>(xp, wkv1 + 256 * 256, bkv1 + 256,
                                          ctxb, kb);
    gemm_k<1><<<1024, 256, 0, stream>>>(kb, wf1, bf1, vb, nullptr);   // x_w' -> vb
    // ---- stage 2 (axis = H) ----
    line_ctx<1><<<1024, 256, 0, stream>>>(vb, wkv2, wq02, bkv2, ctxb);
    val_gate<1><<<1024, 256, 0, stream>>>(vb, wkv2 + 256 * 256, bkv2 + 256,
                                          ctxb, kb);
    gemm_k<2><<<1024, 256, 0, stream>>>(kb, wf2, bf2, nullptr, out);
    (void)in_sizes; (void)n_in; (void)out_size; (void)ws_size;
}